// Round 4
// baseline (795.139 us; speedup 1.0000x reference)
//
#include <hip/hip_runtime.h>
#include <stdint.h>

#define B 4
#define N 16384
#define D 512
#define H 256
#define NROWS (B * N)
#define K_SEL 11468
#define N_TOP 10322
#define N_RAND 1146
#define N_REM (N - N_TOP) /* 6062 */
#define HALF_CNT ((B * N_REM) / 2) /* 12124 */

typedef float v2f __attribute__((ext_vector_type(2)));
typedef float v4f __attribute__((ext_vector_type(4)));

// acc.(lo,hi) += (x.lo, x.lo) * (w.lo, w.hi)
#define PKV_LO(acc, x, w)                                            \
  asm("v_pk_fma_f32 %0, %1, %2, %0 op_sel_hi:[0,1,1]"                \
      : "+v"(acc)                                                    \
      : "v"(x), "v"(w))
// acc.(lo,hi) += (x.hi, x.hi) * (w.lo, w.hi)
#define PKV_HI(acc, x, w)                                            \
  asm("v_pk_fma_f32 %0, %1, %2, %0 op_sel:[1,0,0] op_sel_hi:[1,1,1]" \
      : "+v"(acc)                                                    \
      : "v"(x), "v"(w))

// Monotone float -> uint key (larger float => larger key). No NaNs expected.
__device__ __forceinline__ uint32_t f2key(float x) {
  uint32_t u = __float_as_uint(x);
  return u ^ ((u & 0x80000000u) ? 0xFFFFFFFFu : 0x80000000u);
}

// ---- K0: weight quads: wq[k2*256+j] = {WV[2k2][j],WU[2k2][j],WV[2k2+1][j],WU[2k2+1][j]}
__global__ __launch_bounds__(256) void wprep_kernel(
    const float* __restrict__ WV, const float* __restrict__ WU,
    float* __restrict__ wqf) {
  const int k2 = blockIdx.x;  // 0..255
  const int j = threadIdx.x;  // 0..255
  v4f p;
  p.x = WV[(2 * k2) * H + j];
  p.y = WU[(2 * k2) * H + j];
  p.z = WV[(2 * k2 + 1) * H + j];
  p.w = WU[(2 * k2 + 1) * H + j];
  *(reinterpret_cast<v4f*>(wqf) + (k2 * H + j)) = p;
}

// ---- K1: fused gated-attention raw scores. 2048 blocks x 256 thr (4 waves).
// Wave w owns cols j = w*64+lane (1 per lane); all 4 waves share 32 rows.
// x staged in LDS (32x64 tile, broadcast ds_read_b128); w double-buffered
// through L1 (v4f = 2 k's of (wv,wu)). acc = v2f (V,U) per row -> 64 VGPRs.
// k-order / pk sequence / reduction tree bit-identical to R3 -> raw
// bit-identical -> selection unchanged.
__global__ __launch_bounds__(256, 4) void score_kernel(
    const float* __restrict__ feat, const float* __restrict__ wqf,
    const float* __restrict__ bV, const float* __restrict__ bU,
    const float* __restrict__ watt, const float* __restrict__ batt,
    float* __restrict__ raw) {
  __shared__ float tile[32 * 64];  // 8 KB
  __shared__ float red[32][4];
  const int tid = threadIdx.x;
  const int lane = tid & 63;
  const int w = __builtin_amdgcn_readfirstlane(tid >> 6);  // 0..3
  const int j = w * 64 + lane;
  const int row0 = blockIdx.x * 32;

  v2f acc[32];
#pragma unroll
  for (int r = 0; r < 32; ++r) acc[r] = v2f{0.f, 0.f};

  const v4f* wq = reinterpret_cast<const v4f*>(wqf) + j;  // + k2*256

  for (int kt = 0; kt < D; kt += 64) {
    __syncthreads();
    // stage 32 rows x 64 floats (8 KB): 512 quads, 256 threads x 2
#pragma unroll
    for (int i = 0; i < 2; ++i) {
      const int e = tid + i * 256;
      const int rr = e >> 4, qq = e & 15;  // 16 quads per row
      *reinterpret_cast<v4f*>(&tile[rr * 64 + qq * 4]) =
          *reinterpret_cast<const v4f*>(
              &feat[(size_t)(row0 + rr) * D + kt + qq * 4]);
    }
    __syncthreads();

    const int k2base = kt >> 1;
    v4f wA = wq[(size_t)k2base * 256];
    v4f wB = wq[(size_t)(k2base + 1) * 256];
#pragma unroll 1
    for (int u = 0; u < 16; ++u) {
      v4f wAn, wBn;
      if (u < 15) {
        wAn = wq[(size_t)(k2base + 2 * (u + 1)) * 256];
        wBn = wq[(size_t)(k2base + 2 * (u + 1) + 1) * 256];
      }
      const v2f wA01 = __builtin_shufflevector(wA, wA, 0, 1);
      const v2f wA23 = __builtin_shufflevector(wA, wA, 2, 3);
      const v2f wB01 = __builtin_shufflevector(wB, wB, 0, 1);
      const v2f wB23 = __builtin_shufflevector(wB, wB, 2, 3);
#pragma unroll
      for (int r = 0; r < 32; ++r) {
        const v4f x4 = *reinterpret_cast<const v4f*>(&tile[r * 64 + u * 4]);
        const v2f x01 = __builtin_shufflevector(x4, x4, 0, 1);
        const v2f x23 = __builtin_shufflevector(x4, x4, 2, 3);
        PKV_LO(acc[r], x01, wA01);
        PKV_HI(acc[r], x01, wA23);
        PKV_LO(acc[r], x23, wB01);
        PKV_HI(acc[r], x23, wB23);
      }
      wA = wAn;
      wB = wBn;
    }
  }

  // epilogue: bit-identical structure to R3 (j-block [64w,64w+64) -> slot w)
  const float bv = bV[j], bu = bU[j], wa = watt[j];
#pragma unroll 1
  for (int r = 0; r < 32; ++r) {
    const float aV = tanhf(acc[r].x + bv);
    const float aU = 1.0f / (1.0f + expf(-(acc[r].y + bu)));
    float g = aV * aU * wa;
    for (int off = 32; off > 0; off >>= 1) g += __shfl_down(g, off, 64);
    if (lane == 0) red[r][w] = g;
  }
  __syncthreads();
  if (tid < 32)
    raw[row0 + tid] =
        red[tid][0] + red[tid][1] + red[tid][2] + red[tid][3] + batt[0];
}

// ---- Threefry2x32 (jax key(42)) ------------------------------------------
__device__ __forceinline__ void threefry(uint32_t x0, uint32_t x1,
                                         uint32_t& o0, uint32_t& o1) {
  const uint32_t k0 = 0u, k1 = 42u;
  const uint32_t ks[3] = {k0, k1, k0 ^ k1 ^ 0x1BD11BDAu};
  x0 += ks[0];
  x1 += ks[1];
  const int R0[4] = {13, 15, 26, 6}, R1[4] = {17, 29, 16, 24};
#pragma unroll
  for (int i = 0; i < 5; ++i) {
    const int* R = (i & 1) ? R1 : R0;
#pragma unroll
    for (int jr = 0; jr < 4; ++jr) {
      x0 += x1;
      x1 = (x1 << R[jr]) | (x1 >> (32 - R[jr]));
      x1 ^= x0;
    }
    x0 += ks[(i + 1) % 3];
    x1 += ks[(i + 2) % 3] + (uint32_t)(i + 1);
  }
  o0 = x0;
  o1 = x1;
}

// ---- exclusive scan over 1024 per-thread counts --------------------------
__device__ __forceinline__ int scan1024(int c, int* wred, int tid) {
  const int lane = tid & 63, w = tid >> 6;
  int v = c;
#pragma unroll
  for (int off = 1; off < 64; off <<= 1) {
    const int u = __shfl_up(v, off, 64);
    if (lane >= off) v += u;
  }
  if (lane == 63) wred[w] = v;
  __syncthreads();
  if (tid == 0) {
    int run = 0;
    for (int i = 0; i < 16; ++i) {
      const int a = wred[i];
      wred[i] = run;
      run += a;
    }
  }
  __syncthreads();
  const int res = wred[w] + v - c;
  __syncthreads();
  return res;
}

// ---- K2: fused rand-select + softmax + top-k + membership + compaction ---
__global__ __launch_bounds__(1024) void select_kernel(
    const float* __restrict__ raw, float* __restrict__ attn_out,
    int* __restrict__ sel_ws, float* __restrict__ out_selidx) {
  const int b = blockIdx.x, t = threadIdx.x;
  const int lane = t & 63, w = t >> 6;
  __shared__ float sraw[N];       // 64 KB (phase R: first 6062 words = skey)
  __shared__ int whist[16][256];  // 16 KB
  __shared__ int ghist[256];
  __shared__ int P[256];
  __shared__ int tmp4[4];
  __shared__ int wred[16];
  __shared__ float fred[16];
  __shared__ float shM, shS;
  __shared__ uint32_t sh_prefix;
  __shared__ int sh_rk;
  __shared__ uint32_t pbits[192];

  // ================= Phase R: random selection -> pbits ==================
  uint32_t* skey = reinterpret_cast<uint32_t*>(sraw);
  if (t < 192) pbits[t] = 0;
  for (int p = t; p < N_REM; p += 1024) {
    const int f = b * N_REM + p;
    uint32_t o0, o1, bits;
    if (f < HALF_CNT) {
      threefry((uint32_t)f, (uint32_t)(f + HALF_CNT), o0, o1);
      bits = o0;
    } else {
      threefry((uint32_t)(f - HALF_CNT), (uint32_t)f, o0, o1);
      bits = o1;
    }
    const float u = __uint_as_float((bits >> 9) | 0x3f800000u) - 1.0f;
    skey[p] = f2key(u);
  }
  __syncthreads();
  {
    uint32_t prefix = 0;
    int rk = N_RAND;
    for (int pass = 3; pass >= 0; --pass) {
      const int sh = pass * 8;
      if (t < 256) ghist[t] = 0;
      __syncthreads();
      for (int p = t; p < N_REM; p += 1024) {
        const uint32_t key = skey[p];
        if (pass == 3 || (key >> (sh + 8)) == (prefix >> (sh + 8)))
          atomicAdd(&ghist[(key >> sh) & 255], 1);
      }
      __syncthreads();
      // parallel ascending digit pick: P = inclusive prefix of ghist
      int v = 0;
      if (t < 256) {
        v = ghist[t];
#pragma unroll
        for (int off = 1; off < 64; off <<= 1) {
          const int u = __shfl_up(v, off, 64);
          if (lane >= off) v += u;
        }
        if (lane == 63) tmp4[t >> 6] = v;
      }
      __syncthreads();
      if (t == 0) {
        int run = 0;
        for (int i = 0; i < 4; ++i) {
          const int a = tmp4[i];
          tmp4[i] = run;
          run += a;
        }
      }
      __syncthreads();
      if (t < 256) P[t] = v + tmp4[t >> 6];
      __syncthreads();
      if (t < 256) {
        const int Pm1 = t ? P[t - 1] : 0;
        if (P[t] >= rk && Pm1 < rk) {  // min d with P[d] >= rk
          sh_prefix = prefix | ((uint32_t)t << sh);
          sh_rk = rk - Pm1;
        }
      }
      __syncthreads();
      prefix = sh_prefix;
      rk = sh_rk;
      __syncthreads();
    }
    // stable mark: keys < T, plus first rk ties in ascending p order
    const int CH = 6;  // 1024*6 >= 6062
    const int p0 = t * CH;
    const int pe = (p0 + CH < N_REM) ? p0 + CH : N_REM;
    int ce = 0;
    for (int p = p0; p < pe; ++p) ce += (skey[p] == prefix);
    int ge = scan1024(ce, wred, t);
    for (int p = p0; p < pe; ++p) {
      const uint32_t key = skey[p];
      const bool pick = (key < prefix) || (key == prefix && ge < rk);
      ge += (key == prefix);
      if (pick) atomicOr(&pbits[p >> 5], 1u << (p & 31));
    }
  }
  __syncthreads();

  // ================= Phase S: load raw + softmax =========================
  const float* r = raw + b * N;
  float m = -3.0e38f;
  for (int i = 0; i < 16; ++i) {
    const int idx = t + i * 1024;
    const float v = r[idx];
    sraw[idx] = v;
    m = fmaxf(m, v);
  }
  for (int off = 32; off > 0; off >>= 1) m = fmaxf(m, __shfl_down(m, off, 64));
  if (lane == 0) fred[w] = m;
  __syncthreads();
  if (t == 0) {
    float mm = fred[0];
    for (int i = 1; i < 16; ++i) mm = fmaxf(mm, fred[i]);
    shM = mm;
  }
  __syncthreads();
  const float M = shM;
  float s = 0.f;
  for (int i = 0; i < 16; ++i) s += expf(sraw[t + i * 1024] - M);
  for (int off = 32; off > 0; off >>= 1) s += __shfl_down(s, off, 64);
  if (lane == 0) fred[w] = s;
  __syncthreads();
  if (t == 0) {
    float ss = 0.f;
    for (int i = 0; i < 16; ++i) ss += fred[i];
    shS = ss;
  }
  __syncthreads();
  const float inv = 1.0f / shS;
  for (int i = 0; i < 16; ++i) {
    const int idx = t + i * 1024;
    attn_out[b * N + idx] = expf(sraw[idx] - M) * inv;
  }

  // ================= Phase T: top-k threshold (descending radix) =========
  uint32_t prefix = 0;
  int rk = N_TOP;
  for (int pass = 3; pass >= 0; --pass) {
    const int sh = pass * 8;
#pragma unroll
    for (int q = 0; q < 4; ++q) whist[w][lane * 4 + q] = 0;
    __syncthreads();
    for (int i = 0; i < 16; ++i) {
      const uint32_t key = f2key(sraw[t + i * 1024]);
      if (pass == 3 || (key >> (sh + 8)) == (prefix >> (sh + 8)))
        atomicAdd(&whist[w][(key >> sh) & 255], 1);
    }
    __syncthreads();
    if (t < 256) {
      int tot = 0;
      for (int ww = 0; ww < 16; ++ww) tot += whist[ww][t];
      ghist[t] = tot;
    }
    __syncthreads();
    int v = 0;
    if (t < 256) {
      v = ghist[t];
#pragma unroll
      for (int off = 1; off < 64; off <<= 1) {
        const int u = __shfl_up(v, off, 64);
        if (lane >= off) v += u;
      }
      if (lane == 63) tmp4[t >> 6] = v;
    }
    __syncthreads();
    if (t == 0) {
      int run = 0;
      for (int i = 0; i < 4; ++i) {
        const int a = tmp4[i];
        tmp4[i] = run;
        run += a;
      }
    }
    __syncthreads();
    if (t < 256) P[t] = v + tmp4[t >> 6];
    __syncthreads();
    if (t < 256) {
      // max d with (#keys in digits > d) < rk  <=>  P[d-1] <= TOT-rk < P[d]
      const int TOT = P[255];
      const int Q = TOT - rk;
      const int Pm1 = t ? P[t - 1] : 0;
      if (Pm1 <= Q && P[t] > Q) {
        sh_prefix = prefix | ((uint32_t)t << sh);
        sh_rk = rk - (TOT - P[t]);
      }
    }
    __syncthreads();
    prefix = sh_prefix;
    rk = sh_rk;
    __syncthreads();
  }
  const uint32_t T = prefix;
  const int tieTake = rk;

  // ============ Phase C: membership + p-rank + pbits + compaction ========
  const int n0 = t * 16;
  int cgt = 0, ceq = 0;
  for (int i = 0; i < 16; ++i) {
    const uint32_t key = f2key(sraw[n0 + i]);
    cgt += (key > T);
    ceq += (key == T);
  }
  const int gbase = scan1024(cgt, wred, t);
  const int ebase = scan1024(ceq, wred, t);
  int grun = gbase, erun = ebase;
  unsigned selmask = 0;
  int csel = 0;
  for (int i = 0; i < 16; ++i) {
    const int n = n0 + i;
    const uint32_t key = f2key(sraw[n]);
    const bool gt = key > T, eq = key == T;
    const bool mem = gt || (eq && erun < tieTake);
    int sel;
    if (mem) {
      sel = 1;
    } else {
      const int members_before = grun + (erun < tieTake ? erun : tieTake);
      const int p = n - members_before;
      sel = (int)((pbits[p >> 5] >> (p & 31)) & 1u);
    }
    selmask |= (unsigned)sel << i;
    csel += sel;
    grun += gt;
    erun += eq;
  }
  int q = scan1024(csel, wred, t);
  for (int i = 0; i < 16; ++i) {
    if ((selmask >> i) & 1) {
      const int n = n0 + i;
      sel_ws[b * K_SEL + q] = n;
      out_selidx[b * K_SEL + q] = (float)n;
      ++q;
    }
  }
}

// ---- K3: gather selected feature rows ------------------------------------
__global__ __launch_bounds__(128) void gather_kernel(
    const float* __restrict__ feat, const int* __restrict__ sel_ws,
    float* __restrict__ out_sel) {
  const int qa = blockIdx.x;
  const int b = qa / K_SEL;
  const int n = sel_ws[qa];
  const float4* src =
      reinterpret_cast<const float4*>(feat + (size_t)(b * N + n) * D);
  float4* dst = reinterpret_cast<float4*>(out_sel + (size_t)qa * D);
  dst[threadIdx.x] = src[threadIdx.x];
}

extern "C" void kernel_launch(void* const* d_in, const int* in_sizes, int n_in,
                              void* d_out, int out_size, void* d_ws,
                              size_t ws_size, hipStream_t stream) {
  const float* feat = (const float*)d_in[0];
  const float* WV = (const float*)d_in[1];
  const float* bV = (const float*)d_in[2];
  const float* WU = (const float*)d_in[3];
  const float* bU = (const float*)d_in[4];
  const float* watt = (const float*)d_in[5];
  const float* batt = (const float*)d_in[6];

  float* out = (float*)d_out;
  float* out_selected = out;                      // B*K_SEL*D floats
  float* out_attn = out + (size_t)B * K_SEL * D;  // B*N floats
  float* out_selidx = out_attn + (size_t)B * N;   // B*K_SEL floats

  float* wqf = (float*)d_ws;                   // (D/2)*H*4 = 262144 floats
  float* raw = wqf + (size_t)(D / 2) * H * 4;  // NROWS floats
  int* sel_ws = (int*)(raw + NROWS);           // B*K_SEL

  wprep_kernel<<<D / 2, 256, 0, stream>>>(WV, WU, wqf);
  score_kernel<<<NROWS / 32, 256, 0, stream>>>(feat, wqf, bV, bU, watt, batt,
                                               raw);
  select_kernel<<<B, 1024, 0, stream>>>(raw, out_attn, sel_ws, out_selidx);
  gather_kernel<<<B * K_SEL, 128, 0, stream>>>(feat, sel_ws, out_selected);
}